// Round 2
// baseline (1207.496 us; speedup 1.0000x reference)
//
#include <hip/hip_runtime.h>
#include <hip/hip_bf16.h>
#include <cstdint>
#include <cstddef>

#define NHEADS 16
#define HDIM   88
#define SEQLEN 577
#define NBATCH 32
#define DMODEL 1408
#define MROWS  (NBATCH * SEQLEN)   /* 18464 */
#define MTILES 145
#define MPAD   (MTILES * 128)      /* 18560 */
#define SP     592                 /* padded seq rows per (b,h) */
#define DP     96                  /* padded head dim */
#define NFREQ  44
#define NBH    (NBATCH * NHEADS)   /* 512 */
#define PADELEMS 6056              /* per-(bh,buffer) pad elements: 15*96 + 577*8 */

typedef __attribute__((ext_vector_type(8))) short short8;
typedef __attribute__((ext_vector_type(4))) short short4v;
typedef __attribute__((ext_vector_type(4))) float floatx4;

__device__ __forceinline__ unsigned short f2bf(float f) {
    union { float f; unsigned u; } v; v.f = f;
    unsigned u = v.u;
    u += 0x7fffu + ((u >> 16) & 1u);          // RNE
    return (unsigned short)(u >> 16);
}

__device__ __forceinline__ void gload_lds16(const void* g, void* lds) {
    __builtin_amdgcn_global_load_lds(
        (__attribute__((address_space(1))) unsigned int*)(void*)(g ? (void*)g : (void*)g),
        (__attribute__((address_space(3))) unsigned int*)lds, 16, 0, 0);
}

// ---------------- rope table: cos/sin [SEQLEN][NFREQ] ----------------
__global__ void l4v_rope_table(float* __restrict__ cos_t, float* __restrict__ sin_t) {
    int idx = blockIdx.x * blockDim.x + threadIdx.x;
    if (idx >= SEQLEN * NFREQ) return;
    int s = idx / NFREQ, j = idx % NFREQ;
    float ang = 0.0f;
    if (s != SEQLEN - 1) {
        int coord = (j < 22) ? (s % 24) : (s / 24);
        int i = (j < 22) ? j : j - 22;
        float rf = __expf(-(2.0f * (float)i / 44.0f) * 9.21034037197618f); // ln(10000)
        ang = (float)(coord + 1) * rf;
    }
    cos_t[idx] = cosf(ang);
    sin_t[idx] = sinf(ang);
}

// ---------------- fp32 -> bf16 convert ----------------
__global__ void l4v_cvt_bf16(const float* __restrict__ in, unsigned short* __restrict__ out, int n) {
    int i = (blockIdx.x * blockDim.x + threadIdx.x) * 4;
    if (i + 3 < n) {
        float4 f = *(const float4*)(in + i);
        ushort4 o;
        o.x = f2bf(f.x); o.y = f2bf(f.y); o.z = f2bf(f.z); o.w = f2bf(f.w);
        *(ushort4*)(out + i) = o;
    } else {
        for (; i < n; i++) out[i] = f2bf(in[i]);
    }
}

// ---------------- zero never-written pad regions of qb/kb/vb ----------------
// Per (bh): rows 577..591 (all 96 cols) and rows 0..576 cols 88..95.
// GEMMs later overwrite the live region; pads stay zero every call, so the
// attention kernel never reads uninitialized workspace.
__global__ void l4v_padzero(unsigned short* __restrict__ qb,
                            unsigned short* __restrict__ kb,
                            unsigned short* __restrict__ vb) {
    int idx = blockIdx.x * blockDim.x + threadIdx.x;
    if (idx >= NBH * PADELEMS) return;
    int bh = idx / PADELEMS, r = idx % PADELEMS;
    size_t off;
    if (r < 15 * 96) {
        int row = SEQLEN + r / 96, col = r % 96;
        off = ((size_t)bh * SP + row) * DP + col;
    } else {
        int rr = r - 15 * 96;
        int row = rr / 8, col = 88 + (rr % 8);
        off = ((size_t)bh * SP + row) * DP + col;
    }
    qb[off] = 0; kb[off] = 0; vb[off] = 0;
}

// ---------------- 128x128 bf16 MFMA GEMM, C = A @ Bw^T + bias ----------------
// A [MPAD][DMODEL] bf16 row-major, Bw [DMODEL][DMODEL] bf16 row-major (row=n, k contig)
// mode 0: Q (rope, store bf16 [bh][SP][DP]); 1: K (same); 2: V (no rope, same);
// mode 3: out-proj (store fp32 to d_out [MROWS][DMODEL])
__global__ __launch_bounds__(256, 2)
void l4v_gemm128(const unsigned short* __restrict__ A,
                 const unsigned short* __restrict__ Bw,
                 const float* __restrict__ bias,
                 const float* __restrict__ cos_t,
                 const float* __restrict__ sin_t,
                 unsigned short* __restrict__ out_bf,
                 float* __restrict__ out_f32,
                 int mode)
{
    __shared__ __align__(16) unsigned short a_sm[128 * 32];
    __shared__ __align__(16) unsigned short b_sm[128 * 32];

    const int tid  = threadIdx.x;
    const int lane = tid & 63;
    const int w    = tid >> 6;
    const int quad = lane >> 4;
    const int c    = lane & 15;
    const int wr   = w >> 1;
    const int wc   = w & 1;
    const int m0   = blockIdx.y * 128;
    const int n0   = blockIdx.x * 128;

    floatx4 acc[4][4];
#pragma unroll
    for (int i = 0; i < 4; i++)
#pragma unroll
        for (int j = 0; j < 4; j++) acc[i][j] = (floatx4)0.0f;

    const int chunk0 = w * 128 + lane;
    const int chunk1 = w * 128 + 64 + lane;
    const int r0 = chunk0 >> 2, ch0 = chunk0 & 3;
    const int r1 = chunk1 >> 2, ch1 = chunk1 & 3;
    const unsigned short* Ab = A  + (size_t)m0 * DMODEL;
    const unsigned short* Bb = Bw + (size_t)n0 * DMODEL;

    for (int k0 = 0; k0 < DMODEL; k0 += 32) {
        gload_lds16(Ab + (size_t)r0 * DMODEL + k0 + ch0 * 8, a_sm + (w * 128) * 8);
        gload_lds16(Ab + (size_t)r1 * DMODEL + k0 + ch1 * 8, a_sm + (w * 128 + 64) * 8);
        gload_lds16(Bb + (size_t)r0 * DMODEL + k0 + ch0 * 8, b_sm + (w * 128) * 8);
        gload_lds16(Bb + (size_t)r1 * DMODEL + k0 + ch1 * 8, b_sm + (w * 128 + 64) * 8);
        __syncthreads();
        short8 af[4], bfr[4];
#pragma unroll
        for (int mt = 0; mt < 4; mt++)
            af[mt] = *(const short8*)(a_sm + (wr * 64 + mt * 16 + c) * 32 + quad * 8);
#pragma unroll
        for (int nt = 0; nt < 4; nt++)
            bfr[nt] = *(const short8*)(b_sm + (wc * 64 + nt * 16 + c) * 32 + quad * 8);
#pragma unroll
        for (int mt = 0; mt < 4; mt++)
#pragma unroll
            for (int nt = 0; nt < 4; nt++)
                acc[mt][nt] = __builtin_amdgcn_mfma_f32_16x16x32_bf16(af[mt], bfr[nt], acc[mt][nt], 0, 0, 0);
        __syncthreads();
    }

    // ---------------- epilogue ----------------
    if (mode == 3) {
#pragma unroll
        for (int mt = 0; mt < 4; mt++) {
            int mbase = m0 + wr * 64 + mt * 16 + quad * 4;
#pragma unroll
            for (int nt = 0; nt < 4; nt++) {
                int n = n0 + wc * 64 + nt * 16 + c;
                float bi = bias[n];
#pragma unroll
                for (int r = 0; r < 4; r++) {
                    int m = mbase + r;
                    if (m < MROWS) out_f32[(size_t)m * DMODEL + n] = acc[mt][nt][r] + bi;
                }
            }
        }
        return;
    }

    const bool rope = (mode < 2);
#pragma unroll
    for (int mt = 0; mt < 4; mt++) {
        int mbase = m0 + wr * 64 + mt * 16 + quad * 4;
#pragma unroll
        for (int nt = 0; nt < 4; nt++) {
            int n = n0 + wc * 64 + nt * 16 + c;
            float bi = bias[n];
            int h = n / HDIM, d = n % HDIM, j = d >> 1;
#pragma unroll
            for (int r = 0; r < 4; r++) {
                int m = mbase + r;
                int s = m % SEQLEN;
                int b = m / SEQLEN;
                float v = acc[mt][nt][r] + bi;
                float outv = v;
                if (rope) {
                    float pv = __shfl_xor(v, 1);   // partner element of the complex pair
                    float cs = cos_t[s * NFREQ + j];
                    float sn = sin_t[s * NFREQ + j];
                    outv = ((d & 1) == 0) ? (v * cs - pv * sn) : (pv * sn + v * cs);
                }
                if (m < MROWS)
                    out_bf[((size_t)(b * NHEADS + h) * SP + s) * DP + d] = f2bf(outv);
            }
        }
    }
}

// ---------------- flash attention ----------------
// grid (10, 512): x = q-tile (64 rows), y = (b*16+h). block = 256 (4 waves, 16 q-rows each)
// V is transposed tile-locally in LDS: v_sm [64][96] (gload_lds, round-0 path) is
// read back with ds_read_b128 and scattered into v_tr[96][68] (stride-68 pad +
// 4-short-chunk XOR swizzle). PV B-fragments become two ds_read_b64 (~2-way,
// free) instead of 96 scalar 4-way-conflicted ds_read_u16 per thread per tile.
// Barrier proof: v_tr writes(kt) after A(kt); PV v_tr reads(kt) after B(kt);
// next writes after A(kt+1) > PV(kt). k_sm/v_sm gloads(kt+1) issued after B(kt),
// all LDS reads of tile kt complete before B(kt). Two barriers per tile suffice.
__global__ __launch_bounds__(256, 2)
void l4v_attn(const unsigned short* __restrict__ Q,
              const unsigned short* __restrict__ K,
              const unsigned short* __restrict__ V,
              unsigned short* __restrict__ Obuf)
{
    __shared__ __align__(16) unsigned short k_sm[64 * DP];      // 12288 B
    __shared__ __align__(16) unsigned short v_sm[64 * DP];      // 12288 B
    __shared__ __align__(16) unsigned short v_tr[96 * 68];      // 13056 B
    __shared__ __align__(16) unsigned short p_sm[4][16 * 68];   //  8704 B

    const int tid  = threadIdx.x;
    const int lane = tid & 63;
    const int w    = tid >> 6;
    const int quad = lane >> 4;
    const int c    = lane & 15;
    const int qt   = blockIdx.x;
    const int bh   = blockIdx.y;
    const size_t base = (size_t)bh * SP * DP;

    // Q fragments (A-operand): row = qt*64 + w*16 + c, k = ks*32 + quad*8 + j
    short8 aq[3];
    {
        int qrow = qt * 64 + w * 16 + c;
        if (qrow > SP - 1) qrow = SP - 1;
#pragma unroll
        for (int ks = 0; ks < 3; ks++)
            aq[ks] = *(const short8*)(Q + base + (size_t)qrow * DP + ks * 32 + quad * 8);
    }

    float m_run[4], l_run[4];
    floatx4 o_acc[6];
#pragma unroll
    for (int r = 0; r < 4; r++) { m_run[r] = -INFINITY; l_run[r] = 0.0f; }
#pragma unroll
    for (int i = 0; i < 6; i++) o_acc[i] = (floatx4)0.0f;

    const float sl2e = 0.10660035817780522f * 1.4426950408889634f; // (1/sqrt(88))*log2(e)

    for (int kt = 0; kt < 10; kt++) {
        // stage K,V tiles [64][DP] via global_load_lds (round-0 path, verified)
#pragma unroll
        for (int i = 0; i < 3; i++) {
            int chnk = w * 192 + i * 64 + lane;
            int row = chnk / 12, ch = chnk % 12;
            int krow = kt * 64 + row;
            if (krow > SP - 1) krow = SP - 1;
            gload_lds16(K + base + (size_t)krow * DP + ch * 8, k_sm + (w * 192 + i * 64) * 8);
            gload_lds16(V + base + (size_t)krow * DP + ch * 8, v_sm + (w * 192 + i * 64) * 8);
        }
        __syncthreads();    // A: k_sm/v_sm ready; also orders v_tr writes after prev PV reads

        // scores: 4 s_k sub-tiles x 3 k-steps
        floatx4 sc[4];
#pragma unroll
        for (int nt = 0; nt < 4; nt++) {
            sc[nt] = (floatx4)0.0f;
#pragma unroll
            for (int ks = 0; ks < 3; ks++) {
                short8 bk = *(const short8*)(k_sm + (nt * 16 + c) * DP + ks * 32 + quad * 8);
                sc[nt] = __builtin_amdgcn_mfma_f32_16x16x32_bf16(aq[ks], bk, sc[nt], 0, 0, 0);
            }
        }

        // read back staged V chunks (vector) and transpose-scatter into v_tr
        // v_tr layout: row d (96), 68-short stride, 4-short chunk swizzled by d&15
#pragma unroll
        for (int i = 0; i < 3; i++) {
            int chnk = w * 192 + i * 64 + lane;
            int srow = chnk / 12, ch = chnk % 12;
            short8 vv = *(const short8*)(v_sm + srow * DP + ch * 8);
#pragma unroll
            for (int jj = 0; jj < 8; jj++) {
                int d = ch * 8 + jj;
                v_tr[d * 68 + (((srow >> 2) ^ (d & 15)) << 2) + (srow & 3)] =
                    (unsigned short)vv[jj];
            }
        }

        // masked, scaled (in log2 units)
        float t[4][4];
#pragma unroll
        for (int nt = 0; nt < 4; nt++) {
            int skcol = kt * 64 + nt * 16 + c;
            bool valid = (skcol < SEQLEN);
#pragma unroll
            for (int r = 0; r < 4; r++)
                t[nt][r] = valid ? sc[nt][r] * sl2e : -INFINITY;
        }

        float mnew[4], alpha[4];
#pragma unroll
        for (int r = 0; r < 4; r++) {
            float v = fmaxf(fmaxf(t[0][r], t[1][r]), fmaxf(t[2][r], t[3][r]));
#pragma unroll
            for (int off = 1; off < 16; off <<= 1) v = fmaxf(v, __shfl_xor(v, off));
            mnew[r] = fmaxf(m_run[r], v);
            alpha[r] = exp2f(m_run[r] - mnew[r]);
            m_run[r] = mnew[r];
        }

        float p[4][4];
#pragma unroll
        for (int nt = 0; nt < 4; nt++)
#pragma unroll
            for (int r = 0; r < 4; r++)
                p[nt][r] = exp2f(t[nt][r] - mnew[r]);

#pragma unroll
        for (int r = 0; r < 4; r++) {
            float sm = p[0][r] + p[1][r] + p[2][r] + p[3][r];
#pragma unroll
            for (int off = 1; off < 16; off <<= 1) sm += __shfl_xor(sm, off);
            l_run[r] = l_run[r] * alpha[r] + sm;
        }

        // P -> LDS (C-layout -> A-layout transpose), wave-private, stride 68
#pragma unroll
        for (int nt = 0; nt < 4; nt++)
#pragma unroll
            for (int r = 0; r < 4; r++)
                p_sm[w][(quad * 4 + r) * 68 + nt * 16 + c] = f2bf(p[nt][r]);

        // rescale O
#pragma unroll
        for (int i = 0; i < 6; i++)
#pragma unroll
            for (int r = 0; r < 4; r++)
                o_acc[i][r] *= alpha[r];

        __syncthreads();    // B: v_tr complete (all waves); tile-kt LDS reads done

        // PV: A = P (m = q-row), B = V (k = s_k, n = d) — vector b64 reads
#pragma unroll
        for (int kp = 0; kp < 2; kp++) {
            short8 ap;
            {
                short4v lo = *(const short4v*)(&p_sm[w][c * 68 + kp * 32 + quad * 8]);
                short4v hi = *(const short4v*)(&p_sm[w][c * 68 + kp * 32 + quad * 8 + 4]);
#pragma unroll
                for (int t4 = 0; t4 < 4; t4++) { ap[t4] = lo[t4]; ap[t4 + 4] = hi[t4]; }
            }
#pragma unroll
            for (int d2 = 0; d2 < 6; d2++) {
                int drow = d2 * 16 + c;
                int c4 = kp * 8 + quad * 2;
                short4v lo = *(const short4v*)(v_tr + drow * 68 + (((c4 + 0) ^ c) << 2));
                short4v hi = *(const short4v*)(v_tr + drow * 68 + (((c4 + 1) ^ c) << 2));
                short8 bv;
#pragma unroll
                for (int t4 = 0; t4 < 4; t4++) { bv[t4] = lo[t4]; bv[t4 + 4] = hi[t4]; }
                o_acc[d2] = __builtin_amdgcn_mfma_f32_16x16x32_bf16(ap, bv, o_acc[d2], 0, 0, 0);
            }
        }
    }

    // store: row = b*577 + s_q, col = h*88 + d  (bf16 into attn buffer)
    const int b = bh >> 4, h = bh & 15;
#pragma unroll
    for (int r = 0; r < 4; r++) {
        int sq = qt * 64 + w * 16 + quad * 4 + r;
        float il = 1.0f / l_run[r];
        if (sq < SEQLEN) {
            size_t rowoff = ((size_t)b * SEQLEN + sq) * DMODEL + h * HDIM;
#pragma unroll
            for (int d2 = 0; d2 < 6; d2++) {
                int d = d2 * 16 + c;
                if (d < HDIM) Obuf[rowoff + d] = f2bf(o_acc[d2][r] * il);
            }
        }
    }
}

// ---------------- launcher ----------------
extern "C" void kernel_launch(void* const* d_in, const int* in_sizes, int n_in,
                              void* d_out, int out_size, void* d_ws, size_t ws_size,
                              hipStream_t stream)
{
    const float* hs = (const float*)d_in[0];
    const float* wq = (const float*)d_in[1];
    const float* bq = (const float*)d_in[2];
    const float* wk = (const float*)d_in[3];
    const float* bk = (const float*)d_in[4];
    const float* wv = (const float*)d_in[5];
    const float* bv = (const float*)d_in[6];
    const float* wo = (const float*)d_in[7];
    const float* bo = (const float*)d_in[8];
    float* out = (float*)d_out;

    char* ws = (char*)d_ws;
    size_t off = 0;
    auto alloc = [&](size_t bytes) -> char* {
        char* p = ws + off;
        off += (bytes + 255) & ~(size_t)255;
        return p;
    };

    unsigned short* hs_bf = (unsigned short*)alloc((size_t)MPAD * DMODEL * 2);
    unsigned short* wq_bf = (unsigned short*)alloc((size_t)DMODEL * DMODEL * 2);
    unsigned short* wk_bf = (unsigned short*)alloc((size_t)DMODEL * DMODEL * 2);
    unsigned short* wv_bf = (unsigned short*)alloc((size_t)DMODEL * DMODEL * 2);
    unsigned short* wo_bf = (unsigned short*)alloc((size_t)DMODEL * DMODEL * 2);
    unsigned short* qb    = (unsigned short*)alloc((size_t)NBH * SP * DP * 2);
    unsigned short* kb    = (unsigned short*)alloc((size_t)NBH * SP * DP * 2);
    unsigned short* vbuf  = (unsigned short*)alloc((size_t)NBH * SP * DP * 2);
    float* cos_t = (float*)alloc((size_t)SEQLEN * NFREQ * 4);
    float* sin_t = (float*)alloc((size_t)SEQLEN * NFREQ * 4);
    unsigned short* attn_bf = hs_bf;  // alias: hs_bf dead after QKV GEMMs

    if (off > ws_size) return;  // workspace too small: fail validation cleanly

    l4v_rope_table<<<dim3((SEQLEN * NFREQ + 255) / 256), dim3(256), 0, stream>>>(cos_t, sin_t);
    l4v_padzero<<<dim3((NBH * PADELEMS + 255) / 256), dim3(256), 0, stream>>>(qb, kb, vbuf);

    const int nhs = MROWS * DMODEL;          // 25,997,312 (divisible by 4)
    l4v_cvt_bf16<<<dim3(nhs / 4 / 256), dim3(256), 0, stream>>>(hs, hs_bf, nhs);
    const int nw = DMODEL * DMODEL;          // 1,982,464 (divisible by 4)
    l4v_cvt_bf16<<<dim3(nw / 4 / 256), dim3(256), 0, stream>>>(wq, wq_bf, nw);
    l4v_cvt_bf16<<<dim3(nw / 4 / 256), dim3(256), 0, stream>>>(wk, wk_bf, nw);
    l4v_cvt_bf16<<<dim3(nw / 4 / 256), dim3(256), 0, stream>>>(wv, wv_bf, nw);
    l4v_cvt_bf16<<<dim3(nw / 4 / 256), dim3(256), 0, stream>>>(wo, wo_bf, nw);

    dim3 ggrid(DMODEL / 128, MTILES);  // (11, 145)
    l4v_gemm128<<<ggrid, dim3(256), 0, stream>>>(hs_bf, wq_bf, bq, cos_t, sin_t, qb, nullptr, 0);
    l4v_gemm128<<<ggrid, dim3(256), 0, stream>>>(hs_bf, wk_bf, bk, cos_t, sin_t, kb, nullptr, 1);
    l4v_gemm128<<<ggrid, dim3(256), 0, stream>>>(hs_bf, wv_bf, bv, cos_t, sin_t, vbuf, nullptr, 2);

    l4v_attn<<<dim3(10, NBH), dim3(256), 0, stream>>>(qb, kb, vbuf, attn_bf);

    l4v_gemm128<<<ggrid, dim3(256), 0, stream>>>(attn_bf, wo_bf, bo, cos_t, sin_t, nullptr, out, 3);
}

// Round 3
// 1032.928 us; speedup vs baseline: 1.1690x; 1.1690x over previous
//
#include <hip/hip_runtime.h>
#include <hip/hip_bf16.h>
#include <cstdint>
#include <cstddef>

#define NHEADS 16
#define HDIM   88
#define SEQLEN 577
#define NBATCH 32
#define DMODEL 1408
#define MROWS  (NBATCH * SEQLEN)   /* 18464 */
#define MTILES 145
#define MPAD   (MTILES * 128)      /* 18560 */
#define SP     592                 /* padded seq rows per (b,h) */
#define DP     96                  /* padded head dim */
#define NFREQ  44
#define NBH    (NBATCH * NHEADS)   /* 512 */
#define PADELEMS 6056              /* per-(bh,buffer) pad elements: 15*96 + 577*8 */

typedef __attribute__((ext_vector_type(8))) short short8;
typedef __attribute__((ext_vector_type(4))) short short4v;
typedef __attribute__((ext_vector_type(4))) float floatx4;

__device__ __forceinline__ unsigned short f2bf(float f) {
    union { float f; unsigned u; } v; v.f = f;
    unsigned u = v.u;
    u += 0x7fffu + ((u >> 16) & 1u);          // RNE
    return (unsigned short)(u >> 16);
}

__device__ __forceinline__ void gload_lds16(const void* g, void* lds) {
    __builtin_amdgcn_global_load_lds(
        (__attribute__((address_space(1))) unsigned int*)(void*)(g ? (void*)g : (void*)g),
        (__attribute__((address_space(3))) unsigned int*)lds, 16, 0, 0);
}

// ---------------- rope table: cos/sin [SEQLEN][NFREQ] ----------------
__global__ void l4v_rope_table(float* __restrict__ cos_t, float* __restrict__ sin_t) {
    int idx = blockIdx.x * blockDim.x + threadIdx.x;
    if (idx >= SEQLEN * NFREQ) return;
    int s = idx / NFREQ, j = idx % NFREQ;
    float ang = 0.0f;
    if (s != SEQLEN - 1) {
        int coord = (j < 22) ? (s % 24) : (s / 24);
        int i = (j < 22) ? j : j - 22;
        float rf = __expf(-(2.0f * (float)i / 44.0f) * 9.21034037197618f); // ln(10000)
        ang = (float)(coord + 1) * rf;
    }
    cos_t[idx] = cosf(ang);
    sin_t[idx] = sinf(ang);
}

// ---------------- fp32 -> bf16 convert ----------------
__global__ void l4v_cvt_bf16(const float* __restrict__ in, unsigned short* __restrict__ out, int n) {
    int i = (blockIdx.x * blockDim.x + threadIdx.x) * 4;
    if (i + 3 < n) {
        float4 f = *(const float4*)(in + i);
        ushort4 o;
        o.x = f2bf(f.x); o.y = f2bf(f.y); o.z = f2bf(f.z); o.w = f2bf(f.w);
        *(ushort4*)(out + i) = o;
    } else {
        for (; i < n; i++) out[i] = f2bf(in[i]);
    }
}

// ---------------- zero never-written pad regions of qb/kb/vb ----------------
// Per (bh): rows 577..591 (all 96 cols) and rows 0..576 cols 88..95.
// GEMMs later overwrite the live region; pads stay zero every call, so the
// attention kernel never reads uninitialized workspace.
__global__ void l4v_padzero(unsigned short* __restrict__ qb,
                            unsigned short* __restrict__ kb,
                            unsigned short* __restrict__ vb) {
    int idx = blockIdx.x * blockDim.x + threadIdx.x;
    if (idx >= NBH * PADELEMS) return;
    int bh = idx / PADELEMS, r = idx % PADELEMS;
    size_t off;
    if (r < 15 * 96) {
        int row = SEQLEN + r / 96, col = r % 96;
        off = ((size_t)bh * SP + row) * DP + col;
    } else {
        int rr = r - 15 * 96;
        int row = rr / 8, col = 88 + (rr % 8);
        off = ((size_t)bh * SP + row) * DP + col;
    }
    qb[off] = 0; kb[off] = 0; vb[off] = 0;
}

// ---------------- 128x128 bf16 MFMA GEMM, C = A @ Bw^T + bias ----------------
// A [MPAD][DMODEL] bf16 row-major, Bw [DMODEL][DMODEL] bf16 row-major (row=n, k contig)
// mode 0: Q (rope, store bf16 [bh][SP][DP]); 1: K (same); 2: V (no rope, same);
// mode 3: out-proj (store fp32 to d_out [MROWS][DMODEL])
__global__ __launch_bounds__(256, 2)
void l4v_gemm128(const unsigned short* __restrict__ A,
                 const unsigned short* __restrict__ Bw,
                 const float* __restrict__ bias,
                 const float* __restrict__ cos_t,
                 const float* __restrict__ sin_t,
                 unsigned short* __restrict__ out_bf,
                 float* __restrict__ out_f32,
                 int mode)
{
    __shared__ __align__(16) unsigned short a_sm[128 * 32];
    __shared__ __align__(16) unsigned short b_sm[128 * 32];

    const int tid  = threadIdx.x;
    const int lane = tid & 63;
    const int w    = tid >> 6;
    const int quad = lane >> 4;
    const int c    = lane & 15;
    const int wr   = w >> 1;
    const int wc   = w & 1;
    const int m0   = blockIdx.y * 128;
    const int n0   = blockIdx.x * 128;

    floatx4 acc[4][4];
#pragma unroll
    for (int i = 0; i < 4; i++)
#pragma unroll
        for (int j = 0; j < 4; j++) acc[i][j] = (floatx4)0.0f;

    const int chunk0 = w * 128 + lane;
    const int chunk1 = w * 128 + 64 + lane;
    const int r0 = chunk0 >> 2, ch0 = chunk0 & 3;
    const int r1 = chunk1 >> 2, ch1 = chunk1 & 3;
    const unsigned short* Ab = A  + (size_t)m0 * DMODEL;
    const unsigned short* Bb = Bw + (size_t)n0 * DMODEL;

    for (int k0 = 0; k0 < DMODEL; k0 += 32) {
        gload_lds16(Ab + (size_t)r0 * DMODEL + k0 + ch0 * 8, a_sm + (w * 128) * 8);
        gload_lds16(Ab + (size_t)r1 * DMODEL + k0 + ch1 * 8, a_sm + (w * 128 + 64) * 8);
        gload_lds16(Bb + (size_t)r0 * DMODEL + k0 + ch0 * 8, b_sm + (w * 128) * 8);
        gload_lds16(Bb + (size_t)r1 * DMODEL + k0 + ch1 * 8, b_sm + (w * 128 + 64) * 8);
        __syncthreads();
        short8 af[4], bfr[4];
#pragma unroll
        for (int mt = 0; mt < 4; mt++)
            af[mt] = *(const short8*)(a_sm + (wr * 64 + mt * 16 + c) * 32 + quad * 8);
#pragma unroll
        for (int nt = 0; nt < 4; nt++)
            bfr[nt] = *(const short8*)(b_sm + (wc * 64 + nt * 16 + c) * 32 + quad * 8);
#pragma unroll
        for (int mt = 0; mt < 4; mt++)
#pragma unroll
            for (int nt = 0; nt < 4; nt++)
                acc[mt][nt] = __builtin_amdgcn_mfma_f32_16x16x32_bf16(af[mt], bfr[nt], acc[mt][nt], 0, 0, 0);
        __syncthreads();
    }

    // ---------------- epilogue ----------------
    if (mode == 3) {
#pragma unroll
        for (int mt = 0; mt < 4; mt++) {
            int mbase = m0 + wr * 64 + mt * 16 + quad * 4;
#pragma unroll
            for (int nt = 0; nt < 4; nt++) {
                int n = n0 + wc * 64 + nt * 16 + c;
                float bi = bias[n];
#pragma unroll
                for (int r = 0; r < 4; r++) {
                    int m = mbase + r;
                    if (m < MROWS) out_f32[(size_t)m * DMODEL + n] = acc[mt][nt][r] + bi;
                }
            }
        }
        return;
    }

    const bool rope = (mode < 2);
#pragma unroll
    for (int mt = 0; mt < 4; mt++) {
        int mbase = m0 + wr * 64 + mt * 16 + quad * 4;
#pragma unroll
        for (int nt = 0; nt < 4; nt++) {
            int n = n0 + wc * 64 + nt * 16 + c;
            float bi = bias[n];
            int h = n / HDIM, d = n % HDIM, j = d >> 1;
#pragma unroll
            for (int r = 0; r < 4; r++) {
                int m = mbase + r;
                int s = m % SEQLEN;
                int b = m / SEQLEN;
                float v = acc[mt][nt][r] + bi;
                float outv = v;
                if (rope) {
                    float pv = __shfl_xor(v, 1);   // partner element of the complex pair
                    float cs = cos_t[s * NFREQ + j];
                    float sn = sin_t[s * NFREQ + j];
                    outv = ((d & 1) == 0) ? (v * cs - pv * sn) : (pv * sn + v * cs);
                }
                if (m < MROWS)
                    out_bf[((size_t)(b * NHEADS + h) * SP + s) * DP + d] = f2bf(outv);
            }
        }
    }
}

// ---------------- flash attention ----------------
// grid (10, 512): x = q-tile (64 rows), y = (b*16+h). block = 256 (4 waves, 16 q-rows each)
// Round-0 structure (2 barriers, direct V gather) with address permutations only:
//  - k_sm rows padded to 13 chunks (104 shorts): b128 read slots stride 13 (odd mod 8)
//    -> each 8-lane oct covers all 8 bank groups -> conflict-free QK^T reads.
//  - v_sm [64][12 chunks], staged with source-chunk XOR swizzle pos^((row>>3)&3)
//    (bijective on 0..11; read-side key = quad) -> PV scalar gather drops 8-way -> 4-way.
//  - p_sm stride 68: conflict-free writes, 2-way (free) b64 reads.
__global__ __launch_bounds__(256, 2)
void l4v_attn(const unsigned short* __restrict__ Q,
              const unsigned short* __restrict__ K,
              const unsigned short* __restrict__ V,
              unsigned short* __restrict__ Obuf)
{
    __shared__ __align__(16) unsigned short k_sm[64 * 104];     // 13312 B (13-chunk rows, pos 12 = pad)
    __shared__ __align__(16) unsigned short v_sm[64 * 96];      // 12288 B (chunk-pos swizzled)
    __shared__ __align__(16) unsigned short p_sm[4][16 * 68];   //  8704 B

    const int tid  = threadIdx.x;
    const int lane = tid & 63;
    const int w    = tid >> 6;
    const int quad = lane >> 4;
    const int c    = lane & 15;
    const int qt   = blockIdx.x;
    const int bh   = blockIdx.y;
    const size_t base = (size_t)bh * SP * DP;

    // Q fragments (A-operand): row = qt*64 + w*16 + c, k = ks*32 + quad*8 + j
    short8 aq[3];
    {
        int qrow = qt * 64 + w * 16 + c;
        if (qrow > SP - 1) qrow = SP - 1;
#pragma unroll
        for (int ks = 0; ks < 3; ks++)
            aq[ks] = *(const short8*)(Q + base + (size_t)qrow * DP + ks * 32 + quad * 8);
    }

    float m_run[4], l_run[4];
    floatx4 o_acc[6];
#pragma unroll
    for (int r = 0; r < 4; r++) { m_run[r] = -INFINITY; l_run[r] = 0.0f; }
#pragma unroll
    for (int i = 0; i < 6; i++) o_acc[i] = (floatx4)0.0f;

    const float sl2e = 0.10660035817780522f * 1.4426950408889634f; // (1/sqrt(88))*log2(e)

    for (int kt = 0; kt < 10; kt++) {
        // stage K: 64 rows x 13 chunks (832 chunks); chunk pos 12 is a dummy (pad)
#pragma unroll
        for (int i = 0; i < 4; i++) {
            int chnk = i * 256 + tid;
            if (chnk < 64 * 13) {   // i=3: true iff w==0 (wave-uniform)
                int row = chnk / 13, pos = chnk - row * 13;
                int gpos = (pos < 12) ? pos : 0;     // pad chunk: harmless duplicate
                int krow = kt * 64 + row;
                if (krow > SP - 1) krow = SP - 1;
                gload_lds16(K + base + (size_t)krow * DP + gpos * 8, k_sm + chnk * 8);
            }
        }
        // stage V: 64 rows x 12 chunks (768), source chunk-pos XOR'd by (row>>3)&3
#pragma unroll
        for (int i = 0; i < 3; i++) {
            int chnk = i * 256 + tid;
            int row = chnk / 12, pos = chnk - row * 12;
            int gpos = pos ^ ((row >> 3) & 3);
            int krow = kt * 64 + row;
            if (krow > SP - 1) krow = SP - 1;
            gload_lds16(V + base + (size_t)krow * DP + gpos * 8, v_sm + chnk * 8);
        }
        __syncthreads();

        // scores: 4 s_k sub-tiles x 3 k-steps (row stride 104 shorts)
        floatx4 sc[4];
#pragma unroll
        for (int nt = 0; nt < 4; nt++) {
            sc[nt] = (floatx4)0.0f;
#pragma unroll
            for (int ks = 0; ks < 3; ks++) {
                short8 bk = *(const short8*)(k_sm + (nt * 16 + c) * 104 + ks * 32 + quad * 8);
                sc[nt] = __builtin_amdgcn_mfma_f32_16x16x32_bf16(aq[ks], bk, sc[nt], 0, 0, 0);
            }
        }

        // masked, scaled (in log2 units)
        float t[4][4];
#pragma unroll
        for (int nt = 0; nt < 4; nt++) {
            int skcol = kt * 64 + nt * 16 + c;
            bool valid = (skcol < SEQLEN);
#pragma unroll
            for (int r = 0; r < 4; r++)
                t[nt][r] = valid ? sc[nt][r] * sl2e : -INFINITY;
        }

        float mnew[4], alpha[4];
#pragma unroll
        for (int r = 0; r < 4; r++) {
            float v = fmaxf(fmaxf(t[0][r], t[1][r]), fmaxf(t[2][r], t[3][r]));
#pragma unroll
            for (int off = 1; off < 16; off <<= 1) v = fmaxf(v, __shfl_xor(v, off));
            mnew[r] = fmaxf(m_run[r], v);
            alpha[r] = exp2f(m_run[r] - mnew[r]);
            m_run[r] = mnew[r];
        }

        float p[4][4];
#pragma unroll
        for (int nt = 0; nt < 4; nt++)
#pragma unroll
            for (int r = 0; r < 4; r++)
                p[nt][r] = exp2f(t[nt][r] - mnew[r]);

#pragma unroll
        for (int r = 0; r < 4; r++) {
            float sm = p[0][r] + p[1][r] + p[2][r] + p[3][r];
#pragma unroll
            for (int off = 1; off < 16; off <<= 1) sm += __shfl_xor(sm, off);
            l_run[r] = l_run[r] * alpha[r] + sm;
        }

        // P -> LDS (C-layout -> A-layout transpose), wave-private, stride 68
#pragma unroll
        for (int nt = 0; nt < 4; nt++)
#pragma unroll
            for (int r = 0; r < 4; r++)
                p_sm[w][(quad * 4 + r) * 68 + nt * 16 + c] = f2bf(p[nt][r]);

        // rescale O
#pragma unroll
        for (int i = 0; i < 6; i++)
#pragma unroll
            for (int r = 0; r < 4; r++)
                o_acc[i][r] *= alpha[r];

        // PV: A = P (m = q-row), B = V (k = s_k, n = d); gather with XOR-quad swizzle
#pragma unroll
        for (int kp = 0; kp < 2; kp++) {
            short8 ap;
            {
                short4v lo = *(const short4v*)(&p_sm[w][c * 68 + kp * 32 + quad * 8]);
                short4v hi = *(const short4v*)(&p_sm[w][c * 68 + kp * 32 + quad * 8 + 4]);
#pragma unroll
                for (int t4 = 0; t4 < 4; t4++) { ap[t4] = lo[t4]; ap[t4 + 4] = hi[t4]; }
            }
#pragma unroll
            for (int d2 = 0; d2 < 6; d2++) {
                int posx = (((d2 * 2 + (c >> 3)) ^ quad) << 3) + (c & 7);
                short8 bv;
#pragma unroll
                for (int j = 0; j < 8; j++)
                    bv[j] = (short)v_sm[(kp * 32 + quad * 8 + j) * 96 + posx];
                o_acc[d2] = __builtin_amdgcn_mfma_f32_16x16x32_bf16(ap, bv, o_acc[d2], 0, 0, 0);
            }
        }
        __syncthreads();
    }

    // store: row = b*577 + s_q, col = h*88 + d  (bf16 into attn buffer)
    const int b = bh >> 4, h = bh & 15;
#pragma unroll
    for (int r = 0; r < 4; r++) {
        int sq = qt * 64 + w * 16 + quad * 4 + r;
        float il = 1.0f / l_run[r];
        if (sq < SEQLEN) {
            size_t rowoff = ((size_t)b * SEQLEN + sq) * DMODEL + h * HDIM;
#pragma unroll
            for (int d2 = 0; d2 < 6; d2++) {
                int d = d2 * 16 + c;
                if (d < HDIM) Obuf[rowoff + d] = f2bf(o_acc[d2][r] * il);
            }
        }
    }
}

// ---------------- launcher ----------------
extern "C" void kernel_launch(void* const* d_in, const int* in_sizes, int n_in,
                              void* d_out, int out_size, void* d_ws, size_t ws_size,
                              hipStream_t stream)
{
    const float* hs = (const float*)d_in[0];
    const float* wq = (const float*)d_in[1];
    const float* bq = (const float*)d_in[2];
    const float* wk = (const float*)d_in[3];
    const float* bk = (const float*)d_in[4];
    const float* wv = (const float*)d_in[5];
    const float* bv = (const float*)d_in[6];
    const float* wo = (const float*)d_in[7];
    const float* bo = (const float*)d_in[8];
    float* out = (float*)d_out;

    char* ws = (char*)d_ws;
    size_t off = 0;
    auto alloc = [&](size_t bytes) -> char* {
        char* p = ws + off;
        off += (bytes + 255) & ~(size_t)255;
        return p;
    };

    unsigned short* hs_bf = (unsigned short*)alloc((size_t)MPAD * DMODEL * 2);
    unsigned short* wq_bf = (unsigned short*)alloc((size_t)DMODEL * DMODEL * 2);
    unsigned short* wk_bf = (unsigned short*)alloc((size_t)DMODEL * DMODEL * 2);
    unsigned short* wv_bf = (unsigned short*)alloc((size_t)DMODEL * DMODEL * 2);
    unsigned short* wo_bf = (unsigned short*)alloc((size_t)DMODEL * DMODEL * 2);
    unsigned short* qb    = (unsigned short*)alloc((size_t)NBH * SP * DP * 2);
    unsigned short* kb    = (unsigned short*)alloc((size_t)NBH * SP * DP * 2);
    unsigned short* vbuf  = (unsigned short*)alloc((size_t)NBH * SP * DP * 2);
    float* cos_t = (float*)alloc((size_t)SEQLEN * NFREQ * 4);
    float* sin_t = (float*)alloc((size_t)SEQLEN * NFREQ * 4);
    unsigned short* attn_bf = hs_bf;  // alias: hs_bf dead after QKV GEMMs

    if (off > ws_size) return;  // workspace too small: fail validation cleanly

    l4v_rope_table<<<dim3((SEQLEN * NFREQ + 255) / 256), dim3(256), 0, stream>>>(cos_t, sin_t);
    l4v_padzero<<<dim3((NBH * PADELEMS + 255) / 256), dim3(256), 0, stream>>>(qb, kb, vbuf);

    const int nhs = MROWS * DMODEL;          // 25,997,312 (divisible by 4)
    l4v_cvt_bf16<<<dim3(nhs / 4 / 256), dim3(256), 0, stream>>>(hs, hs_bf, nhs);
    const int nw = DMODEL * DMODEL;          // 1,982,464 (divisible by 4)
    l4v_cvt_bf16<<<dim3(nw / 4 / 256), dim3(256), 0, stream>>>(wq, wq_bf, nw);
    l4v_cvt_bf16<<<dim3(nw / 4 / 256), dim3(256), 0, stream>>>(wk, wk_bf, nw);
    l4v_cvt_bf16<<<dim3(nw / 4 / 256), dim3(256), 0, stream>>>(wv, wv_bf, nw);
    l4v_cvt_bf16<<<dim3(nw / 4 / 256), dim3(256), 0, stream>>>(wo, wo_bf, nw);

    dim3 ggrid(DMODEL / 128, MTILES);  // (11, 145)
    l4v_gemm128<<<ggrid, dim3(256), 0, stream>>>(hs_bf, wq_bf, bq, cos_t, sin_t, qb, nullptr, 0);
    l4v_gemm128<<<ggrid, dim3(256), 0, stream>>>(hs_bf, wk_bf, bk, cos_t, sin_t, kb, nullptr, 1);
    l4v_gemm128<<<ggrid, dim3(256), 0, stream>>>(hs_bf, wv_bf, bv, cos_t, sin_t, vbuf, nullptr, 2);

    l4v_attn<<<dim3(10, NBH), dim3(256), 0, stream>>>(qb, kb, vbuf, attn_bf);

    l4v_gemm128<<<ggrid, dim3(256), 0, stream>>>(attn_bf, wo_bf, bo, cos_t, sin_t, nullptr, out, 3);
}

// Round 4
// 1013.971 us; speedup vs baseline: 1.1909x; 1.0187x over previous
//
#include <hip/hip_runtime.h>
#include <hip/hip_bf16.h>
#include <cstdint>
#include <cstddef>

#define NHEADS 16
#define HDIM   88
#define SEQLEN 577
#define NBATCH 32
#define DMODEL 1408
#define MROWS  (NBATCH * SEQLEN)   /* 18464 */
#define MTILES 145
#define MPAD   (MTILES * 128)      /* 18560 */
#define SP     592                 /* padded seq rows per (b,h) */
#define DP     96                  /* padded head dim */
#define SPAD   592                 /* seq cols in transposed V */
#define NFREQ  44
#define NBH    (NBATCH * NHEADS)   /* 512 */
#define PADELEMS 6056              /* per-(bh,buffer) pad elements: 15*96 + 577*8 */

typedef __attribute__((ext_vector_type(8))) short short8;
typedef __attribute__((ext_vector_type(4))) short short4v;
typedef __attribute__((ext_vector_type(4))) float floatx4;

__device__ __forceinline__ unsigned short f2bf(float f) {
    union { float f; unsigned u; } v; v.f = f;
    unsigned u = v.u;
    u += 0x7fffu + ((u >> 16) & 1u);          // RNE
    return (unsigned short)(u >> 16);
}

__device__ __forceinline__ void gload_lds16(const void* g, void* lds) {
    __builtin_amdgcn_global_load_lds(
        (__attribute__((address_space(1))) unsigned int*)(void*)(g ? (void*)g : (void*)g),
        (__attribute__((address_space(3))) unsigned int*)lds, 16, 0, 0);
}

// ---------------- rope table: cos/sin [SEQLEN][NFREQ] ----------------
__global__ void l4v_rope_table(float* __restrict__ cos_t, float* __restrict__ sin_t) {
    int idx = blockIdx.x * blockDim.x + threadIdx.x;
    if (idx >= SEQLEN * NFREQ) return;
    int s = idx / NFREQ, j = idx % NFREQ;
    float ang = 0.0f;
    if (s != SEQLEN - 1) {
        int coord = (j < 22) ? (s % 24) : (s / 24);
        int i = (j < 22) ? j : j - 22;
        float rf = __expf(-(2.0f * (float)i / 44.0f) * 9.21034037197618f); // ln(10000)
        ang = (float)(coord + 1) * rf;
    }
    cos_t[idx] = cosf(ang);
    sin_t[idx] = sinf(ang);
}

// ---------------- fp32 -> bf16 convert ----------------
__global__ void l4v_cvt_bf16(const float* __restrict__ in, unsigned short* __restrict__ out, int n) {
    int i = (blockIdx.x * blockDim.x + threadIdx.x) * 4;
    if (i + 3 < n) {
        float4 f = *(const float4*)(in + i);
        ushort4 o;
        o.x = f2bf(f.x); o.y = f2bf(f.y); o.z = f2bf(f.z); o.w = f2bf(f.w);
        *(ushort4*)(out + i) = o;
    } else {
        for (; i < n; i++) out[i] = f2bf(in[i]);
    }
}

// ---------------- zero never-written pad regions of qb/kb/vb ----------------
__global__ void l4v_padzero(unsigned short* __restrict__ qb,
                            unsigned short* __restrict__ kb,
                            unsigned short* __restrict__ vb) {
    int idx = blockIdx.x * blockDim.x + threadIdx.x;
    if (idx >= NBH * PADELEMS) return;
    int bh = idx / PADELEMS, r = idx % PADELEMS;
    size_t off;
    if (r < 15 * 96) {
        int row = SEQLEN + r / 96, col = r % 96;
        off = ((size_t)bh * SP + row) * DP + col;
    } else {
        int rr = r - 15 * 96;
        int row = rr / 8, col = 88 + (rr % 8);
        off = ((size_t)bh * SP + row) * DP + col;
    }
    qb[off] = 0; kb[off] = 0; vb[off] = 0;
}

// ---------------- V transpose: vbuf [bh][s(592)][d(96)] -> vt [bh][d(96)][s(592)] ----------------
// grid (37, 512): x = 16-row s-tile, y = bh. Reads fully-initialized vbuf (padzero),
// writes EVERY element of vt each call (deterministic across graph replays).
// LDS tile [16 s][104] (13 slots/row, odd -> decorrelated banks both sides).
__global__ __launch_bounds__(256)
void l4v_vtr(const unsigned short* __restrict__ vb, unsigned short* __restrict__ vt) {
    __shared__ __align__(16) unsigned short t_sm[16 * 104];
    const int tid = threadIdx.x;
    const int bh  = blockIdx.y;
    const int s0  = blockIdx.x * 16;
    const size_t ibase = (size_t)bh * SP * DP;
    const size_t obase = (size_t)bh * DP * SPAD;
    if (tid < 192) {
        int row = tid / 12, ch = tid % 12;
        short8 v = *(const short8*)(vb + ibase + (size_t)(s0 + row) * DP + ch * 8);
        *(short8*)(t_sm + row * 104 + ch * 8) = v;
    }
    __syncthreads();
    if (tid < 192) {
        int d = tid >> 1, sc = tid & 1;
        short8 o;
#pragma unroll
        for (int j = 0; j < 8; j++) o[j] = (short)t_sm[(sc * 8 + j) * 104 + d];
        *(short8*)(vt + obase + (size_t)d * SPAD + s0 + sc * 8) = o;
    }
}

// ---------------- 128x128 bf16 MFMA GEMM, C = A @ Bw^T + bias ----------------
__global__ __launch_bounds__(256, 2)
void l4v_gemm128(const unsigned short* __restrict__ A,
                 const unsigned short* __restrict__ Bw,
                 const float* __restrict__ bias,
                 const float* __restrict__ cos_t,
                 const float* __restrict__ sin_t,
                 unsigned short* __restrict__ out_bf,
                 float* __restrict__ out_f32,
                 int mode)
{
    __shared__ __align__(16) unsigned short a_sm[128 * 32];
    __shared__ __align__(16) unsigned short b_sm[128 * 32];

    const int tid  = threadIdx.x;
    const int lane = tid & 63;
    const int w    = tid >> 6;
    const int quad = lane >> 4;
    const int c    = lane & 15;
    const int wr   = w >> 1;
    const int wc   = w & 1;
    const int m0   = blockIdx.y * 128;
    const int n0   = blockIdx.x * 128;

    floatx4 acc[4][4];
#pragma unroll
    for (int i = 0; i < 4; i++)
#pragma unroll
        for (int j = 0; j < 4; j++) acc[i][j] = (floatx4)0.0f;

    const int chunk0 = w * 128 + lane;
    const int chunk1 = w * 128 + 64 + lane;
    const int r0 = chunk0 >> 2, ch0 = chunk0 & 3;
    const int r1 = chunk1 >> 2, ch1 = chunk1 & 3;
    const unsigned short* Ab = A  + (size_t)m0 * DMODEL;
    const unsigned short* Bb = Bw + (size_t)n0 * DMODEL;

    for (int k0 = 0; k0 < DMODEL; k0 += 32) {
        gload_lds16(Ab + (size_t)r0 * DMODEL + k0 + ch0 * 8, a_sm + (w * 128) * 8);
        gload_lds16(Ab + (size_t)r1 * DMODEL + k0 + ch1 * 8, a_sm + (w * 128 + 64) * 8);
        gload_lds16(Bb + (size_t)r0 * DMODEL + k0 + ch0 * 8, b_sm + (w * 128) * 8);
        gload_lds16(Bb + (size_t)r1 * DMODEL + k0 + ch1 * 8, b_sm + (w * 128 + 64) * 8);
        __syncthreads();
        short8 af[4], bfr[4];
#pragma unroll
        for (int mt = 0; mt < 4; mt++)
            af[mt] = *(const short8*)(a_sm + (wr * 64 + mt * 16 + c) * 32 + quad * 8);
#pragma unroll
        for (int nt = 0; nt < 4; nt++)
            bfr[nt] = *(const short8*)(b_sm + (wc * 64 + nt * 16 + c) * 32 + quad * 8);
#pragma unroll
        for (int mt = 0; mt < 4; mt++)
#pragma unroll
            for (int nt = 0; nt < 4; nt++)
                acc[mt][nt] = __builtin_amdgcn_mfma_f32_16x16x32_bf16(af[mt], bfr[nt], acc[mt][nt], 0, 0, 0);
        __syncthreads();
    }

    // ---------------- epilogue ----------------
    if (mode == 3) {
#pragma unroll
        for (int mt = 0; mt < 4; mt++) {
            int mbase = m0 + wr * 64 + mt * 16 + quad * 4;
#pragma unroll
            for (int nt = 0; nt < 4; nt++) {
                int n = n0 + wc * 64 + nt * 16 + c;
                float bi = bias[n];
#pragma unroll
                for (int r = 0; r < 4; r++) {
                    int m = mbase + r;
                    if (m < MROWS) out_f32[(size_t)m * DMODEL + n] = acc[mt][nt][r] + bi;
                }
            }
        }
        return;
    }

    const bool rope = (mode < 2);
#pragma unroll
    for (int mt = 0; mt < 4; mt++) {
        int mbase = m0 + wr * 64 + mt * 16 + quad * 4;
#pragma unroll
        for (int nt = 0; nt < 4; nt++) {
            int n = n0 + wc * 64 + nt * 16 + c;
            float bi = bias[n];
            int h = n / HDIM, d = n % HDIM, j = d >> 1;
#pragma unroll
            for (int r = 0; r < 4; r++) {
                int m = mbase + r;
                int s = m % SEQLEN;
                int b = m / SEQLEN;
                float v = acc[mt][nt][r] + bi;
                float outv = v;
                if (rope) {
                    float pv = __shfl_xor(v, 1);   // partner element of the complex pair
                    float cs = cos_t[s * NFREQ + j];
                    float sn = sin_t[s * NFREQ + j];
                    outv = ((d & 1) == 0) ? (v * cs - pv * sn) : (pv * sn + v * cs);
                }
                if (m < MROWS)
                    out_bf[((size_t)(b * NHEADS + h) * SP + s) * DP + d] = f2bf(outv);
            }
        }
    }
}

// ---------------- flash attention ----------------
// grid (10, 512). 4 waves, 16 q-rows each.
//  - k_sm [64][104] (13 slots, odd): QK^T b128 reads conflict-free (quarter-wave
//    phase (5c+quad) mod 8 covers each bank-group exactly 2x).
//  - v_sm = V^T tile [96 d][72] (9 slots, odd): PV B-fragment is ONE b128 read
//    (was 96 scalar ds_read_u16 + 96 v_mov): phase (c+quad) mod 8 -> conflict-free.
//  - p_sm stride 68: conflict-free writes, 2-way (free) b64 reads.
__global__ __launch_bounds__(256, 2)
void l4v_attn(const unsigned short* __restrict__ Q,
              const unsigned short* __restrict__ K,
              const unsigned short* __restrict__ Vt,
              unsigned short* __restrict__ Obuf)
{
    __shared__ __align__(16) unsigned short k_sm[64 * 104];     // 13312 B
    __shared__ __align__(16) unsigned short v_sm[96 * 72];      // 13824 B
    __shared__ __align__(16) unsigned short p_sm[4][16 * 68];   //  8704 B

    const int tid  = threadIdx.x;
    const int lane = tid & 63;
    const int w    = tid >> 6;
    const int quad = lane >> 4;
    const int c    = lane & 15;
    const int qt   = blockIdx.x;
    const int bh   = blockIdx.y;
    const size_t base = (size_t)bh * SP * DP;
    const size_t vtb  = (size_t)bh * DP * SPAD;

    // Q fragments (A-operand): row = qt*64 + w*16 + c, k = ks*32 + quad*8 + j
    short8 aq[3];
    {
        int qrow = qt * 64 + w * 16 + c;
        if (qrow > SP - 1) qrow = SP - 1;
#pragma unroll
        for (int ks = 0; ks < 3; ks++)
            aq[ks] = *(const short8*)(Q + base + (size_t)qrow * DP + ks * 32 + quad * 8);
    }

    float m_run[4], l_run[4];
    floatx4 o_acc[6];
#pragma unroll
    for (int r = 0; r < 4; r++) { m_run[r] = -INFINITY; l_run[r] = 0.0f; }
#pragma unroll
    for (int i = 0; i < 6; i++) o_acc[i] = (floatx4)0.0f;

    const float sl2e = 0.10660035817780522f * 1.4426950408889634f; // (1/sqrt(88))*log2(e)

    for (int kt = 0; kt < 10; kt++) {
        // stage K: 64 rows x 13 chunks (832); chunk pos 12 = dummy pad
#pragma unroll
        for (int i = 0; i < 4; i++) {
            int chnk = i * 256 + tid;
            if (chnk < 64 * 13) {
                int row = chnk / 13, pos = chnk - row * 13;
                int gpos = (pos < 12) ? pos : 0;
                int krow = kt * 64 + row;
                if (krow > SP - 1) krow = SP - 1;
                gload_lds16(K + base + (size_t)krow * DP + gpos * 8, k_sm + chnk * 8);
            }
        }
        // stage V^T: 96 d-rows x 9 chunks (864); pos 8 = dummy; col clamped to 584
        // (kt=9: cols >=592 duplicate zero region s=584..591; P=0 there -> safe)
#pragma unroll
        for (int i = 0; i < 4; i++) {
            int chnk = i * 256 + tid;
            if (chnk < 96 * 9) {
                int row = chnk / 9, pos = chnk - row * 9;
                int col = kt * 64 + (pos & 7) * 8;
                if (col > 584) col = 584;
                gload_lds16(Vt + vtb + (size_t)row * SPAD + col, v_sm + chnk * 8);
            }
        }
        __syncthreads();

        // scores: 4 s_k sub-tiles x 3 k-steps (row stride 104 shorts)
        floatx4 sc[4];
#pragma unroll
        for (int nt = 0; nt < 4; nt++) {
            sc[nt] = (floatx4)0.0f;
#pragma unroll
            for (int ks = 0; ks < 3; ks++) {
                short8 bk = *(const short8*)(k_sm + (nt * 16 + c) * 104 + ks * 32 + quad * 8);
                sc[nt] = __builtin_amdgcn_mfma_f32_16x16x32_bf16(aq[ks], bk, sc[nt], 0, 0, 0);
            }
        }

        // masked, scaled (in log2 units)
        float t[4][4];
#pragma unroll
        for (int nt = 0; nt < 4; nt++) {
            int skcol = kt * 64 + nt * 16 + c;
            bool valid = (skcol < SEQLEN);
#pragma unroll
            for (int r = 0; r < 4; r++)
                t[nt][r] = valid ? sc[nt][r] * sl2e : -INFINITY;
        }

        float mnew[4], alpha[4];
#pragma unroll
        for (int r = 0; r < 4; r++) {
            float v = fmaxf(fmaxf(t[0][r], t[1][r]), fmaxf(t[2][r], t[3][r]));
#pragma unroll
            for (int off = 1; off < 16; off <<= 1) v = fmaxf(v, __shfl_xor(v, off));
            mnew[r] = fmaxf(m_run[r], v);
            alpha[r] = exp2f(m_run[r] - mnew[r]);
            m_run[r] = mnew[r];
        }

        float p[4][4];
#pragma unroll
        for (int nt = 0; nt < 4; nt++)
#pragma unroll
            for (int r = 0; r < 4; r++)
                p[nt][r] = exp2f(t[nt][r] - mnew[r]);

#pragma unroll
        for (int r = 0; r < 4; r++) {
            float sm = p[0][r] + p[1][r] + p[2][r] + p[3][r];
#pragma unroll
            for (int off = 1; off < 16; off <<= 1) sm += __shfl_xor(sm, off);
            l_run[r] = l_run[r] * alpha[r] + sm;
        }

        // P -> LDS (C-layout -> A-layout transpose), wave-private, stride 68
#pragma unroll
        for (int nt = 0; nt < 4; nt++)
#pragma unroll
            for (int r = 0; r < 4; r++)
                p_sm[w][(quad * 4 + r) * 68 + nt * 16 + c] = f2bf(p[nt][r]);

        // rescale O
#pragma unroll
        for (int i = 0; i < 6; i++)
#pragma unroll
            for (int r = 0; r < 4; r++)
                o_acc[i][r] *= alpha[r];

        // PV: A = P (m = q-row), B = V^T rows (n = d, k = s) — single b128 per fragment
#pragma unroll
        for (int kp = 0; kp < 2; kp++) {
            short8 ap;
            {
                short4v lo = *(const short4v*)(&p_sm[w][c * 68 + kp * 32 + quad * 8]);
                short4v hi = *(const short4v*)(&p_sm[w][c * 68 + kp * 32 + quad * 8 + 4]);
#pragma unroll
                for (int t4 = 0; t4 < 4; t4++) { ap[t4] = lo[t4]; ap[t4 + 4] = hi[t4]; }
            }
#pragma unroll
            for (int d2 = 0; d2 < 6; d2++) {
                short8 bv = *(const short8*)(v_sm + (d2 * 16 + c) * 72 + (kp * 4 + quad) * 8);
                o_acc[d2] = __builtin_amdgcn_mfma_f32_16x16x32_bf16(ap, bv, o_acc[d2], 0, 0, 0);
            }
        }
        __syncthreads();
    }

    // store: row = b*577 + s_q, col = h*88 + d  (bf16 into attn buffer)
    const int b = bh >> 4, h = bh & 15;
#pragma unroll
    for (int r = 0; r < 4; r++) {
        int sq = qt * 64 + w * 16 + quad * 4 + r;
        float il = 1.0f / l_run[r];
        if (sq < SEQLEN) {
            size_t rowoff = ((size_t)b * SEQLEN + sq) * DMODEL + h * HDIM;
#pragma unroll
            for (int d2 = 0; d2 < 6; d2++) {
                int d = d2 * 16 + c;
                if (d < HDIM) Obuf[rowoff + d] = f2bf(o_acc[d2][r] * il);
            }
        }
    }
}

// ---------------- launcher ----------------
extern "C" void kernel_launch(void* const* d_in, const int* in_sizes, int n_in,
                              void* d_out, int out_size, void* d_ws, size_t ws_size,
                              hipStream_t stream)
{
    const float* hs = (const float*)d_in[0];
    const float* wq = (const float*)d_in[1];
    const float* bq = (const float*)d_in[2];
    const float* wk = (const float*)d_in[3];
    const float* bk = (const float*)d_in[4];
    const float* wv = (const float*)d_in[5];
    const float* bv = (const float*)d_in[6];
    const float* wo = (const float*)d_in[7];
    const float* bo = (const float*)d_in[8];
    float* out = (float*)d_out;

    char* ws = (char*)d_ws;
    size_t off = 0;
    auto alloc = [&](size_t bytes) -> char* {
        char* p = ws + off;
        off += (bytes + 255) & ~(size_t)255;
        return p;
    };

    unsigned short* hs_bf = (unsigned short*)alloc((size_t)MPAD * DMODEL * 2);
    unsigned short* wq_bf = (unsigned short*)alloc((size_t)DMODEL * DMODEL * 2);
    unsigned short* wk_bf = (unsigned short*)alloc((size_t)DMODEL * DMODEL * 2);
    unsigned short* wv_bf = (unsigned short*)alloc((size_t)DMODEL * DMODEL * 2);
    unsigned short* wo_bf = (unsigned short*)alloc((size_t)DMODEL * DMODEL * 2);
    unsigned short* qb    = (unsigned short*)alloc((size_t)NBH * SP * DP * 2);
    unsigned short* kb    = (unsigned short*)alloc((size_t)NBH * SP * DP * 2);
    unsigned short* vbuf  = (unsigned short*)alloc((size_t)NBH * SP * DP * 2);
    float* cos_t = (float*)alloc((size_t)SEQLEN * NFREQ * 4);
    float* sin_t = (float*)alloc((size_t)SEQLEN * NFREQ * 4);
    unsigned short* attn_bf = hs_bf;  // alias: hs_bf dead after QKV GEMMs
    // vt [NBH][96][SPAD] bf16 = 58.2 MB aliases d_out (104 MB fp32): dead before
    // the final GEMM writes d_out; fully overwritten by l4v_vtr every launch.
    unsigned short* vt = (unsigned short*)out;

    if (off > ws_size) return;  // workspace too small: fail validation cleanly

    l4v_rope_table<<<dim3((SEQLEN * NFREQ + 255) / 256), dim3(256), 0, stream>>>(cos_t, sin_t);
    l4v_padzero<<<dim3((NBH * PADELEMS + 255) / 256), dim3(256), 0, stream>>>(qb, kb, vbuf);

    const int nhs = MROWS * DMODEL;          // 25,997,312 (divisible by 4)
    l4v_cvt_bf16<<<dim3(nhs / 4 / 256), dim3(256), 0, stream>>>(hs, hs_bf, nhs);
    const int nw = DMODEL * DMODEL;          // 1,982,464 (divisible by 4)
    l4v_cvt_bf16<<<dim3(nw / 4 / 256), dim3(256), 0, stream>>>(wq, wq_bf, nw);
    l4v_cvt_bf16<<<dim3(nw / 4 / 256), dim3(256), 0, stream>>>(wk, wk_bf, nw);
    l4v_cvt_bf16<<<dim3(nw / 4 / 256), dim3(256), 0, stream>>>(wv, wv_bf, nw);
    l4v_cvt_bf16<<<dim3(nw / 4 / 256), dim3(256), 0, stream>>>(wo, wo_bf, nw);

    dim3 ggrid(DMODEL / 128, MTILES);  // (11, 145)
    l4v_gemm128<<<ggrid, dim3(256), 0, stream>>>(hs_bf, wq_bf, bq, cos_t, sin_t, qb, nullptr, 0);
    l4v_gemm128<<<ggrid, dim3(256), 0, stream>>>(hs_bf, wk_bf, bk, cos_t, sin_t, kb, nullptr, 1);
    l4v_gemm128<<<ggrid, dim3(256), 0, stream>>>(hs_bf, wv_bf, bv, cos_t, sin_t, vbuf, nullptr, 2);

    l4v_vtr<<<dim3(37, NBH), dim3(256), 0, stream>>>(vbuf, vt);

    l4v_attn<<<dim3(10, NBH), dim3(256), 0, stream>>>(qb, kb, vt, attn_bf);

    l4v_gemm128<<<ggrid, dim3(256), 0, stream>>>(attn_bf, wo_bf, bo, cos_t, sin_t, nullptr, out, 3);
}